// Round 7
// baseline (266.400 us; speedup 1.0000x reference)
//
#include <hip/hip_runtime.h>
#include <hip/hip_fp16.h>
#include <math.h>

// EM routing, hardcoded geometry: CHILD_SPACE=12, K=3, S=1 -> P=10,
// CHILD_CAPS=16, PARENT_CAPS=O=32, POSE=16, N=4, KTOT=144
#define NB     4
#define P      10
#define P2     100
#define CS     12
#define CCAPS  16
#define KTOT   144
#define O      32
#define POSE   16
#define VSZ    73728          // KTOT*O*POSE elems per (b,p)
#define EPSF   1e-9f
#define LNF    22.2222222222222222f   // 100/(144/32)
#define TWO_PI 6.28318530717958647f
#define NBP    400
#define EUNITS (NB*CS*CS*2)   // 1152

#define LAM0 0.0005f          // 0.01*(1-0.95)
#define LAM1 0.000975f        // 0.01*(1-0.95^2)
#define LAM2 0.00142625f      // 0.01*(1-0.95^3)

__device__ float g_zz [NBP*KTOT*O];   // log-posteriors (M output)
__device__ float g_rrp[NBP*KTOT*O];   // rr' = rr * act (E output)

// number of parents covering child coord x (1-D): min(x+1, 3, 12-x)
__device__ __forceinline__ int npar(int x) {
    int a = x + 1, b = CS - x;
    int m = a < 3 ? a : 3;
    return m < b ? m : b;
}

// opaque pin: value becomes an asm in/out -> compiler cannot rematerialize
// the load. Combined with waves_per_eu(4,4) (VGPR budget pinned at 128,
// no occupancy incentive) the values stay in VGPRs instead of spilling.
__device__ __forceinline__ void pin4(float4& v) {
    asm volatile("" : "+v"(v.x), "+v"(v.y), "+v"(v.z), "+v"(v.w));
}
__device__ __forceinline__ void pin2(uint2& u) {
    asm volatile("" : "+v"(u.x), "+v"(u.y));
}

// =========== V400: iter-0 m_step fully fused (fp32) + fp16 convert ==========
// grid 400 (bp), 1024 thr: tid = ks*128 + q, ks=0..7 (18 rows each), q = o*4+c4.
// waves_per_eu(4,4): exactly 1 block/CU, VGPR budget 128 -> vv[18] (72 regs)
// lives in registers across the finish barriers with NO spill. Deletes the
// second 118 MB votes pass (zz from regs).
__global__ __launch_bounds__(1024)
__attribute__((amdgpu_waves_per_eu(4, 4)))
void v400_kernel(const float* __restrict__ votes, const float* __restrict__ acts,
                 __half* __restrict__ hv,
                 const float* __restrict__ beta_v, const float* __restrict__ beta_a,
                 float lam)
{
    __shared__ float  rr1[KTOT];                  // iter-0 rr' (o-independent)
    __shared__ float4 lm1[1024];                  // 16 KB
    __shared__ float4 lm2[1024];                  // 16 KB
    __shared__ float  lss[1024];                  // 4 KB
    __shared__ float4 ml[128];
    __shared__ float4 il[128];
    __shared__ float  zl[O];
    __shared__ float  costl[O];
    __shared__ __align__(16) float zzl[KTOT*O];   // 18 KB

    const int tid = threadIdx.x;
    const int bp  = blockIdx.x;
    const int p   = bp % P2;
    const int pr  = p / P, pc = p - pr * P;
    const int ks  = tid >> 7;          // 0..7, 18 rows each
    const int q   = tid & 127;
    const int o   = q >> 2;
    const int c4  = q & 3;

    if (tid < KTOT) {
        int kslot = tid >> 4;
        int kr = kslot / 3, kc = kslot - kr * 3;
        float ppc = (float)(npar(pr + kr) * npar(pc + kc));
        rr1[tid] = acts[bp * KTOT + tid] / (ppc * 32.0f + EPSF);
    }

    const float* vb = votes + (size_t)bp * VSZ + (size_t)(ks * 18) * 512 + q * 4;
    __half*      hb = hv    + (size_t)bp * VSZ + (size_t)(ks * 18) * 512 + q * 4;

    // pure load burst (18 independent loads in flight), then pin
    float4 vv[18];
    #pragma unroll
    for (int i = 0; i < 18; ++i)
        vv[i] = *(const float4*)(vb + i * 512);
    #pragma unroll
    for (int i = 0; i < 18; ++i)
        pin4(vv[i]);
    __syncthreads();

    // accumulate (register-only)
    float  s  = 0.f;
    float4 m1 = make_float4(0.f, 0.f, 0.f, 0.f);
    float4 m2 = make_float4(0.f, 0.f, 0.f, 0.f);
    #pragma unroll
    for (int i = 0; i < 18; ++i) {
        float  rp = rr1[ks * 18 + i];
        float4 v  = vv[i];
        s += rp;
        m1.x += rp * v.x;       m1.y += rp * v.y;
        m1.z += rp * v.z;       m1.w += rp * v.w;
        m2.x += rp * v.x * v.x; m2.y += rp * v.y * v.y;
        m2.z += rp * v.z * v.z; m2.w += rp * v.w * v.w;
    }
    lm1[tid] = m1; lm2[tid] = m2; lss[tid] = s;

    // hv convert + store burst (fire-and-forget; drains at the barrier)
    #pragma unroll
    for (int i = 0; i < 18; ++i) {
        __half2 ha  = __floats2half2_rn(vv[i].x, vv[i].y);
        __half2 hbv = __floats2half2_rn(vv[i].z, vv[i].w);
        uint2 st;
        st.x = *(unsigned int*)&ha;
        st.y = *(unsigned int*)&hbv;
        *(uint2*)(hb + i * 512) = st;
    }
    __syncthreads();

    float lv2 = 0.f, cost_o = 0.f;
    if (tid < 128) {
        m1 = lm1[tid]; m2 = lm2[tid]; s = lss[tid];
        #pragma unroll
        for (int w = 1; w < 8; ++w) {
            float4 a = lm1[w * 128 + tid];
            float4 b = lm2[w * 128 + tid];
            m1.x += a.x; m1.y += a.y; m1.z += a.z; m1.w += a.w;
            m2.x += b.x; m2.y += b.y; m2.z += b.z; m2.w += b.w;
            s += lss[w * 128 + tid];
        }

        float denom = s + EPSF;
        float4 mean = make_float4(m1.x/denom, m1.y/denom, m1.z/denom, m1.w/denom);
        float4 var;
        var.x = fmaxf(m2.x/denom - mean.x*mean.x, 1e-30f);
        var.y = fmaxf(m2.y/denom - mean.y*mean.y, 1e-30f);
        var.z = fmaxf(m2.z/denom - mean.z*mean.z, 1e-30f);
        var.w = fmaxf(m2.w/denom - mean.w*mean.w, 1e-30f);
        float4 i2 = make_float4(0.5f/var.x, 0.5f/var.y, 0.5f/var.z, 0.5f/var.w);
        ml[tid] = mean; il[tid] = i2;
        float lve = logf(var.x+EPSF)+logf(var.y+EPSF)+logf(var.z+EPSF)+logf(var.w+EPSF);
        float l2  = logf(TWO_PI*var.x)+logf(TWO_PI*var.y)+logf(TWO_PI*var.z)+logf(TWO_PI*var.w);
        lve += __shfl_xor(lve, 1); lve += __shfl_xor(lve, 2);
        l2  += __shfl_xor(l2, 1);  l2  += __shfl_xor(l2, 2);
        lv2 = l2;
        cost_o = (16.f * beta_v[o] + 0.5f * lve) * s * LNF;
        if (c4 == 0) costl[o] = cost_o;
    }
    __syncthreads();
    if (tid < 128) {
        float cm = 0.f;
        #pragma unroll
        for (int i = 0; i < O; ++i) cm += costl[i];
        cm *= (1.f / 32.f);
        float sq = 0.f;
        #pragma unroll
        for (int i = 0; i < O; ++i) { float d = costl[i] - cm; sq += d * d; }
        float cstd = sqrtf(sq * (1.f / 32.f));
        float aj = 1.f / (1.f + expf(-lam * (beta_a[o] + (cm - cost_o) / (cstd + EPSF))));
        if (c4 == 0) zl[o] = logf(aj + EPSF) - 0.5f * lv2;
    }
    __syncthreads();

    // zz pass from register-cached fp32 votes (no global re-read)
    {
        float4 mean = ml[q];
        float4 iv   = il[q];
        float  zp   = zl[o];
        #pragma unroll
        for (int i = 0; i < 18; ++i) {
            float4 v = vv[i];
            float dx = v.x - mean.x, dy = v.y - mean.y;
            float dz = v.z - mean.z, dw = v.w - mean.w;
            float t = dx*dx*iv.x + dy*dy*iv.y + dz*dz*iv.z + dw*dw*iv.w;
            t += __shfl_xor(t, 1); t += __shfl_xor(t, 2);   // 16 pose comps
            if (c4 == 0) zzl[(ks * 18 + i) * O + o] = zp - t;
        }
    }
    __syncthreads();
    float4* dst = (float4*)(g_zz + (size_t)bp * (KTOT * O));
    for (int f = tid; f < KTOT * O / 4; f += 1024)
        dst[f] = ((float4*)zzl)[f];
}

// ============ M16: full m_step from fp16 votes + rr' (grid 400) =============
// 1024 thr: tid = ks*128 + q, ks=0..7 (18 rows each), q = o*4 + c4 (4 comps).
// !LAST: waves_per_eu(4,4) + pinned u[18] (36 regs) -> zz pass from regs,
// hv re-read deleted. LAST: single pass, default allocation.
template<bool LAST>
__global__ __launch_bounds__(1024)
__attribute__((amdgpu_waves_per_eu(4, 4)))
void m16_kernel(const __half* __restrict__ hv,
                const float* __restrict__ beta_v, const float* __restrict__ beta_a,
                float* __restrict__ out, float lam)
{
    __shared__ __align__(16) float rrp[KTOT*O];   // 18 KB; reused as zzl
    __shared__ float4 lm1[1024];                  // 16 KB
    __shared__ float4 lm2[1024];                  // 16 KB
    __shared__ float  lss[1024];                  // 4 KB
    __shared__ float4 ml[128];
    __shared__ float4 il[128];
    __shared__ float  zl[O];
    __shared__ float  costl[O];

    const int tid = threadIdx.x;
    const int bp  = blockIdx.x;
    const int ks  = tid >> 7;
    const int q   = tid & 127;
    const int o   = q >> 2;
    const int c4  = q & 3;

    const __half* vb = hv + (size_t)bp * VSZ + (size_t)(ks * 18) * 512 + q * 4;

    // issue all vote loads first (overlap with rr' staging), pin if reused
    uint2 u[18];
    #pragma unroll
    for (int i = 0; i < 18; ++i)
        u[i] = *(const uint2*)(vb + i * 512);
    if (!LAST) {
        #pragma unroll
        for (int i = 0; i < 18; ++i)
            pin2(u[i]);
    }

    // stage rr'
    for (int f = tid; f < KTOT * O / 4; f += 1024)
        ((float4*)rrp)[f] = ((const float4*)(g_rrp + (size_t)bp * (KTOT * O)))[f];
    __syncthreads();

    float  s  = 0.f;
    float4 m1 = make_float4(0.f, 0.f, 0.f, 0.f);
    float4 m2 = make_float4(0.f, 0.f, 0.f, 0.f);
    #pragma unroll
    for (int i = 0; i < 18; ++i) {
        float rp = rrp[(ks * 18 + i) * O + o];
        float2 a = __half22float2(*(__half2*)&u[i].x);
        float2 b = __half22float2(*(__half2*)&u[i].y);
        s += rp;
        m1.x += rp * a.x;       m1.y += rp * a.y;
        m1.z += rp * b.x;       m1.w += rp * b.y;
        m2.x += rp * a.x * a.x; m2.y += rp * a.y * a.y;
        m2.z += rp * b.x * b.x; m2.w += rp * b.y * b.y;
    }
    lm1[tid] = m1; lm2[tid] = m2; lss[tid] = s;
    __syncthreads();

    float lv2 = 0.f, cost_o = 0.f;
    if (tid < 128) {
        m1 = lm1[tid]; m2 = lm2[tid]; s = lss[tid];
        #pragma unroll
        for (int w = 1; w < 8; ++w) {
            float4 a = lm1[w * 128 + tid];
            float4 b = lm2[w * 128 + tid];
            m1.x += a.x; m1.y += a.y; m1.z += a.z; m1.w += a.w;
            m2.x += b.x; m2.y += b.y; m2.z += b.z; m2.w += b.w;
            s += lss[w * 128 + tid];
        }

        float denom = s + EPSF;
        float4 mean = make_float4(m1.x/denom, m1.y/denom, m1.z/denom, m1.w/denom);
        float4 var;
        var.x = fmaxf(m2.x/denom - mean.x*mean.x, 1e-30f);
        var.y = fmaxf(m2.y/denom - mean.y*mean.y, 1e-30f);
        var.z = fmaxf(m2.z/denom - mean.z*mean.z, 1e-30f);
        var.w = fmaxf(m2.w/denom - mean.w*mean.w, 1e-30f);
        float4 i2 = make_float4(0.5f/var.x, 0.5f/var.y, 0.5f/var.z, 0.5f/var.w);
        ml[tid] = mean; il[tid] = i2;
        float lve = logf(var.x+EPSF)+logf(var.y+EPSF)+logf(var.z+EPSF)+logf(var.w+EPSF);
        float l2  = logf(TWO_PI*var.x)+logf(TWO_PI*var.y)+logf(TWO_PI*var.z)+logf(TWO_PI*var.w);
        lve += __shfl_xor(lve, 1); lve += __shfl_xor(lve, 2);
        l2  += __shfl_xor(l2, 1);  l2  += __shfl_xor(l2, 2);
        lv2 = l2;
        cost_o = (16.f * beta_v[o] + 0.5f * lve) * s * LNF;
        if (c4 == 0) costl[o] = cost_o;
    }
    __syncthreads();
    if (tid < 128) {
        float cm = 0.f;
        #pragma unroll
        for (int i = 0; i < O; ++i) cm += costl[i];
        cm *= (1.f / 32.f);
        float sq = 0.f;
        #pragma unroll
        for (int i = 0; i < O; ++i) { float d = costl[i] - cm; sq += d * d; }
        float cstd = sqrtf(sq * (1.f / 32.f));
        float aj = 1.f / (1.f + expf(-lam * (beta_a[o] + (cm - cost_o) / (cstd + EPSF))));
        if (LAST) {
            ((float4*)out)[bp * 128 + tid] = ml[tid];
            if (c4 == 0) out[(size_t)NBP * 512 + bp * O + o] = aj;
        } else {
            if (c4 == 0) zl[o] = logf(aj + EPSF) - 0.5f * lv2;
        }
    }
    if (LAST) return;
    __syncthreads();

    // zz pass from register-cached fp16 votes; zzl aliases rrp
    {
        float4 mean = ml[q];
        float4 iv   = il[q];
        float  zp   = zl[o];
        #pragma unroll
        for (int i = 0; i < 18; ++i) {
            float2 a = __half22float2(*(__half2*)&u[i].x);
            float2 b = __half22float2(*(__half2*)&u[i].y);
            float dx = a.x - mean.x, dy = a.y - mean.y;
            float dz = b.x - mean.z, dw = b.y - mean.w;
            float t = dx*dx*iv.x + dy*dy*iv.y + dz*dz*iv.z + dw*dw*iv.w;
            t += __shfl_xor(t, 1); t += __shfl_xor(t, 2);   // 16 pose comps
            if (c4 == 0) rrp[(ks * 18 + i) * O + o] = zp - t;
        }
    }
    __syncthreads();
    float4* dst = (float4*)(g_zz + (size_t)bp * (KTOT * O));
    for (int f = tid; f < KTOT * O / 4; f += 1024)
        dst[f] = ((float4*)rrp)[f];
}

// ============ E: segment softmax, writes rr' = rr * act =============
__global__ __launch_bounds__(256)
void e_kernel(const float* __restrict__ acts)
{
    const int tid = threadIdx.x;
    const int u   = blockIdx.x;
    const int b   = u / (CS * CS * 2);
    int r = u - b * (CS * CS * 2);
    const int child = r >> 1, half = r & 1;
    const int cr = child / CS, cl = child - cr * CS;
    const int cc = half * 8 + (tid >> 5), o = tid & 31;

    float zz[9];
    float vmax = -1e30f;
    #pragma unroll
    for (int kr = 0; kr < 3; ++kr) {
        int pr_ = cr - kr;
        #pragma unroll
        for (int kc = 0; kc < 3; ++kc) {
            int pc_ = cl - kc, si = kr * 3 + kc;
            float z = -1e30f;
            if (pr_ >= 0 && pr_ < P && pc_ >= 0 && pc_ < P) {
                int bpp = b * P2 + pr_ * P + pc_;
                z = g_zz[(size_t)bpp * (KTOT * O) + (si * CCAPS + cc) * O + o];
            }
            zz[si] = z;
            vmax = fmaxf(vmax, z);
        }
    }
    vmax = fmaxf(vmax, __shfl_xor(vmax, 1));
    vmax = fmaxf(vmax, __shfl_xor(vmax, 2));
    vmax = fmaxf(vmax, __shfl_xor(vmax, 4));
    vmax = fmaxf(vmax, __shfl_xor(vmax, 8));
    vmax = fmaxf(vmax, __shfl_xor(vmax, 16));

    float ps = 0.f;
    #pragma unroll
    for (int si = 0; si < 9; ++si) {
        float e = (zz[si] > -1e29f) ? expf(zz[si] - vmax) : 0.f;
        zz[si] = e;
        ps += e;
    }
    ps += __shfl_xor(ps, 1);
    ps += __shfl_xor(ps, 2);
    ps += __shfl_xor(ps, 4);
    ps += __shfl_xor(ps, 8);
    ps += __shfl_xor(ps, 16);
    float inv = 1.f / ps;

    #pragma unroll
    for (int kr = 0; kr < 3; ++kr) {
        int pr_ = cr - kr;
        #pragma unroll
        for (int kc = 0; kc < 3; ++kc) {
            int pc_ = cl - kc, si = kr * 3 + kc;
            if (pr_ >= 0 && pr_ < P && pc_ >= 0 && pc_ < P) {
                int bpp = b * P2 + pr_ * P + pc_;
                float av = acts[bpp * KTOT + si * CCAPS + cc];
                g_rrp[(size_t)bpp * (KTOT * O) + (si * CCAPS + cc) * O + o]
                    = zz[si] * inv * av;
            }
        }
    }
}

extern "C" void kernel_launch(void* const* d_in, const int* in_sizes, int n_in,
                              void* d_out, int out_size, void* d_ws, size_t ws_size,
                              hipStream_t stream)
{
    (void)in_sizes; (void)n_in; (void)out_size; (void)ws_size;

    const float* votes = (const float*)d_in[0];
    const float* acts  = (const float*)d_in[1];
    const float* bv    = (const float*)d_in[2];
    const float* ba    = (const float*)d_in[3];
    float* out = (float*)d_out;
    __half* hv = (__half*)d_ws;          // 59 MB fp16 votes copy

    v400_kernel<<<dim3(NBP), dim3(1024), 0, stream>>>(votes, acts, hv, bv, ba, LAM0);
    e_kernel<<<dim3(EUNITS), dim3(256), 0, stream>>>(acts);
    m16_kernel<false><<<dim3(NBP), dim3(1024), 0, stream>>>(hv, bv, ba, out, LAM1);
    e_kernel<<<dim3(EUNITS), dim3(256), 0, stream>>>(acts);
    m16_kernel<true ><<<dim3(NBP), dim3(1024), 0, stream>>>(hv, bv, ba, out, LAM2);
}

// Round 8
// 264.098 us; speedup vs baseline: 1.0087x; 1.0087x over previous
//
#include <hip/hip_runtime.h>
#include <hip/hip_fp16.h>
#include <math.h>

// EM routing, hardcoded geometry: CHILD_SPACE=12, K=3, S=1 -> P=10,
// CHILD_CAPS=16, PARENT_CAPS=O=32, POSE=16, N=4, KTOT=144
#define NB     4
#define P      10
#define P2     100
#define CS     12
#define CCAPS  16
#define KTOT   144
#define O      32
#define POSE   16
#define VSZ    73728          // KTOT*O*POSE elems per (b,p)
#define EPSF   1e-9f
#define LNF    22.2222222222222222f   // 100/(144/32)
#define TWO_PI 6.28318530717958647f
#define NBP    400
#define EUNITS (NB*CS*CS*2)   // 1152

#define LAM0 0.0005f          // 0.01*(1-0.95)
#define LAM1 0.000975f        // 0.01*(1-0.95^2)
#define LAM2 0.00142625f      // 0.01*(1-0.95^3)

__device__ float g_zz [NBP*KTOT*O];   // log-posteriors (M output)
__device__ float g_rrp[NBP*KTOT*O];   // rr' = rr * act (E output)

// number of parents covering child coord x (1-D): min(x+1, 3, 12-x)
__device__ __forceinline__ int npar(int x) {
    int a = x + 1, b = CS - x;
    int m = a < 3 ? a : 3;
    return m < b ? m : b;
}

// =========== V400: iter-0 m_step fully fused (fp32) + fp16 convert ==========
// 512 thr, 4 blocks/CU target: tid = ks*128 + q, ks=0..3 (36 rows), q=o*4+c4.
// LDS union (18 KB): {lm1,lm2,lss} reduction scratch aliases zzl output —
// disjoint phases. Total LDS ~23 KB -> 4 blocks/CU (32 waves), so one
// block's m-loop overlaps another's reduce/zz phases.
// zz pass reads the fp16 hv just written (L2-hot, 59 MB total vs 118 fp32).
__global__ __launch_bounds__(512)
void v400_kernel(const float* __restrict__ votes, const float* __restrict__ acts,
                 __half* __restrict__ hv,
                 const float* __restrict__ beta_v, const float* __restrict__ beta_a,
                 float lam)
{
    __shared__ __align__(16) unsigned char smem[18432];   // union region
    float4* lm1 = (float4*)smem;              // [512]  8 KB
    float4* lm2 = (float4*)(smem + 8192);     // [512]  8 KB
    float*  lss = (float*) (smem + 16384);    // [512]  2 KB
    float*  zzl = (float*) smem;              // [4608] aliases lm*/lss
    __shared__ float  rr1[KTOT];
    __shared__ float4 ml[128];
    __shared__ float4 il[128];
    __shared__ float  zl[O];
    __shared__ float  costl[O];

    const int tid = threadIdx.x;
    const int bp  = blockIdx.x;
    const int p   = bp % P2;
    const int pr  = p / P, pc = p - pr * P;
    const int ks  = tid >> 7;          // 0..3, 36 rows each
    const int q   = tid & 127;
    const int o   = q >> 2;
    const int c4  = q & 3;

    if (tid < KTOT) {
        int kslot = tid >> 4;
        int kr = kslot / 3, kc = kslot - kr * 3;
        float ppc = (float)(npar(pr + kr) * npar(pc + kc));
        rr1[tid] = acts[bp * KTOT + tid] / (ppc * 32.0f + EPSF);
    }
    __syncthreads();

    const float* vb = votes + (size_t)bp * VSZ + (size_t)(ks * 36) * 512 + q * 4;
    __half*      hb = hv    + (size_t)bp * VSZ + (size_t)(ks * 36) * 512 + q * 4;
    float  s  = 0.f;
    float4 m1 = make_float4(0.f, 0.f, 0.f, 0.f);
    float4 m2 = make_float4(0.f, 0.f, 0.f, 0.f);
    #pragma unroll 6
    for (int i = 0; i < 36; ++i) {
        float  rp = rr1[ks * 36 + i];
        float4 v  = *(const float4*)(vb + i * 512);
        s += rp;
        m1.x += rp * v.x;       m1.y += rp * v.y;
        m1.z += rp * v.z;       m1.w += rp * v.w;
        m2.x += rp * v.x * v.x; m2.y += rp * v.y * v.y;
        m2.z += rp * v.z * v.z; m2.w += rp * v.w * v.w;
        __half2 ha  = __floats2half2_rn(v.x, v.y);
        __half2 hbv = __floats2half2_rn(v.z, v.w);
        uint2 st;
        st.x = *(unsigned int*)&ha;
        st.y = *(unsigned int*)&hbv;
        *(uint2*)(hb + i * 512) = st;
    }
    lm1[tid] = m1; lm2[tid] = m2; lss[tid] = s;
    __syncthreads();

    float lv2 = 0.f, cost_o = 0.f;
    if (tid < 128) {
        m1 = lm1[tid]; m2 = lm2[tid]; s = lss[tid];
        #pragma unroll
        for (int w = 1; w < 4; ++w) {
            float4 a = lm1[w * 128 + tid];
            float4 b = lm2[w * 128 + tid];
            m1.x += a.x; m1.y += a.y; m1.z += a.z; m1.w += a.w;
            m2.x += b.x; m2.y += b.y; m2.z += b.z; m2.w += b.w;
            s += lss[w * 128 + tid];
        }

        float denom = s + EPSF;
        float4 mean = make_float4(m1.x/denom, m1.y/denom, m1.z/denom, m1.w/denom);
        float4 var;
        var.x = fmaxf(m2.x/denom - mean.x*mean.x, 1e-30f);
        var.y = fmaxf(m2.y/denom - mean.y*mean.y, 1e-30f);
        var.z = fmaxf(m2.z/denom - mean.z*mean.z, 1e-30f);
        var.w = fmaxf(m2.w/denom - mean.w*mean.w, 1e-30f);
        float4 i2 = make_float4(0.5f/var.x, 0.5f/var.y, 0.5f/var.z, 0.5f/var.w);
        ml[tid] = mean; il[tid] = i2;
        float lve = logf(var.x+EPSF)+logf(var.y+EPSF)+logf(var.z+EPSF)+logf(var.w+EPSF);
        float l2  = logf(TWO_PI*var.x)+logf(TWO_PI*var.y)+logf(TWO_PI*var.z)+logf(TWO_PI*var.w);
        lve += __shfl_xor(lve, 1); lve += __shfl_xor(lve, 2);
        l2  += __shfl_xor(l2, 1);  l2  += __shfl_xor(l2, 2);
        lv2 = l2;
        cost_o = (16.f * beta_v[o] + 0.5f * lve) * s * LNF;
        if (c4 == 0) costl[o] = cost_o;
    }
    __syncthreads();
    if (tid < 128) {
        float cm = 0.f;
        #pragma unroll
        for (int i = 0; i < O; ++i) cm += costl[i];
        cm *= (1.f / 32.f);
        float sq = 0.f;
        #pragma unroll
        for (int i = 0; i < O; ++i) { float d = costl[i] - cm; sq += d * d; }
        float cstd = sqrtf(sq * (1.f / 32.f));
        float aj = 1.f / (1.f + expf(-lam * (beta_a[o] + (cm - cost_o) / (cstd + EPSF))));
        if (c4 == 0) zl[o] = logf(aj + EPSF) - 0.5f * lv2;
    }
    __syncthreads();

    // zz pass from the fp16 hv this block just wrote (L2-hot)
    {
        float4 mean = ml[q];
        float4 iv   = il[q];
        float  zp   = zl[o];
        #pragma unroll 6
        for (int i = 0; i < 36; ++i) {
            uint2 u  = *(const uint2*)(hb + i * 512);
            float2 a = __half22float2(*(__half2*)&u.x);
            float2 b = __half22float2(*(__half2*)&u.y);
            float dx = a.x - mean.x, dy = a.y - mean.y;
            float dz = b.x - mean.z, dw = b.y - mean.w;
            float t = dx*dx*iv.x + dy*dy*iv.y + dz*dz*iv.z + dw*dw*iv.w;
            t += __shfl_xor(t, 1); t += __shfl_xor(t, 2);   // 16 pose comps
            if (c4 == 0) zzl[(ks * 36 + i) * O + o] = zp - t;
        }
    }
    __syncthreads();
    float4* dst = (float4*)(g_zz + (size_t)bp * (KTOT * O));
    for (int f = tid; f < KTOT * O / 4; f += 512)
        dst[f] = ((float4*)zzl)[f];
}

// ============ M16: full m_step from fp16 votes + rr' (grid 400) =============
// 512 thr, same phase/union structure as v400. rrp staged in the union,
// consumed by the m-loop, then the region is reused for lm* and then zzl.
template<bool LAST>
__global__ __launch_bounds__(512)
void m16_kernel(const __half* __restrict__ hv,
                const float* __restrict__ beta_v, const float* __restrict__ beta_a,
                float* __restrict__ out, float lam)
{
    __shared__ __align__(16) unsigned char smem[18432];   // union region
    float*  rrp = (float*) smem;              // [4608] staged rr'
    float4* lm1 = (float4*)smem;              // [512]  (aliases rrp, later)
    float4* lm2 = (float4*)(smem + 8192);
    float*  lss = (float*) (smem + 16384);
    float*  zzl = (float*) smem;              // [4608] (aliases, last)
    __shared__ float4 ml[128];
    __shared__ float4 il[128];
    __shared__ float  zl[O];
    __shared__ float  costl[O];

    const int tid = threadIdx.x;
    const int bp  = blockIdx.x;
    const int ks  = tid >> 7;          // 0..3, 36 rows each
    const int q   = tid & 127;
    const int o   = q >> 2;
    const int c4  = q & 3;

    // stage rr'
    for (int f = tid; f < KTOT * O / 4; f += 512)
        ((float4*)rrp)[f] = ((const float4*)(g_rrp + (size_t)bp * (KTOT * O)))[f];
    __syncthreads();

    const __half* vb = hv + (size_t)bp * VSZ + (size_t)(ks * 36) * 512 + q * 4;
    float  s  = 0.f;
    float4 m1 = make_float4(0.f, 0.f, 0.f, 0.f);
    float4 m2 = make_float4(0.f, 0.f, 0.f, 0.f);
    #pragma unroll 6
    for (int i = 0; i < 36; ++i) {
        float rp = rrp[(ks * 36 + i) * O + o];
        uint2 u  = *(const uint2*)(vb + i * 512);
        float2 a = __half22float2(*(__half2*)&u.x);
        float2 b = __half22float2(*(__half2*)&u.y);
        s += rp;
        m1.x += rp * a.x;       m1.y += rp * a.y;
        m1.z += rp * b.x;       m1.w += rp * b.y;
        m2.x += rp * a.x * a.x; m2.y += rp * a.y * a.y;
        m2.z += rp * b.x * b.x; m2.w += rp * b.y * b.y;
    }
    __syncthreads();                   // rrp dead; safe to overwrite with lm*
    lm1[tid] = m1; lm2[tid] = m2; lss[tid] = s;
    __syncthreads();

    float lv2 = 0.f, cost_o = 0.f;
    if (tid < 128) {
        m1 = lm1[tid]; m2 = lm2[tid]; s = lss[tid];
        #pragma unroll
        for (int w = 1; w < 4; ++w) {
            float4 a = lm1[w * 128 + tid];
            float4 b = lm2[w * 128 + tid];
            m1.x += a.x; m1.y += a.y; m1.z += a.z; m1.w += a.w;
            m2.x += b.x; m2.y += b.y; m2.z += b.z; m2.w += b.w;
            s += lss[w * 128 + tid];
        }

        float denom = s + EPSF;
        float4 mean = make_float4(m1.x/denom, m1.y/denom, m1.z/denom, m1.w/denom);
        float4 var;
        var.x = fmaxf(m2.x/denom - mean.x*mean.x, 1e-30f);
        var.y = fmaxf(m2.y/denom - mean.y*mean.y, 1e-30f);
        var.z = fmaxf(m2.z/denom - mean.z*mean.z, 1e-30f);
        var.w = fmaxf(m2.w/denom - mean.w*mean.w, 1e-30f);
        float4 i2 = make_float4(0.5f/var.x, 0.5f/var.y, 0.5f/var.z, 0.5f/var.w);
        ml[tid] = mean; il[tid] = i2;
        float lve = logf(var.x+EPSF)+logf(var.y+EPSF)+logf(var.z+EPSF)+logf(var.w+EPSF);
        float l2  = logf(TWO_PI*var.x)+logf(TWO_PI*var.y)+logf(TWO_PI*var.z)+logf(TWO_PI*var.w);
        lve += __shfl_xor(lve, 1); lve += __shfl_xor(lve, 2);
        l2  += __shfl_xor(l2, 1);  l2  += __shfl_xor(l2, 2);
        lv2 = l2;
        cost_o = (16.f * beta_v[o] + 0.5f * lve) * s * LNF;
        if (c4 == 0) costl[o] = cost_o;
    }
    __syncthreads();
    if (tid < 128) {
        float cm = 0.f;
        #pragma unroll
        for (int i = 0; i < O; ++i) cm += costl[i];
        cm *= (1.f / 32.f);
        float sq = 0.f;
        #pragma unroll
        for (int i = 0; i < O; ++i) { float d = costl[i] - cm; sq += d * d; }
        float cstd = sqrtf(sq * (1.f / 32.f));
        float aj = 1.f / (1.f + expf(-lam * (beta_a[o] + (cm - cost_o) / (cstd + EPSF))));
        if (LAST) {
            ((float4*)out)[bp * 128 + tid] = ml[tid];
            if (c4 == 0) out[(size_t)NBP * 512 + bp * O + o] = aj;
        } else {
            if (c4 == 0) zl[o] = logf(aj + EPSF) - 0.5f * lv2;
        }
    }
    if (LAST) return;
    __syncthreads();

    // zz pass (fp16 re-read, L2-warm); zzl aliases the union
    {
        float4 mean = ml[q];
        float4 iv   = il[q];
        float  zp   = zl[o];
        #pragma unroll 6
        for (int i = 0; i < 36; ++i) {
            uint2 u  = *(const uint2*)(vb + i * 512);
            float2 a = __half22float2(*(__half2*)&u.x);
            float2 b = __half22float2(*(__half2*)&u.y);
            float dx = a.x - mean.x, dy = a.y - mean.y;
            float dz = b.x - mean.z, dw = b.y - mean.w;
            float t = dx*dx*iv.x + dy*dy*iv.y + dz*dz*iv.z + dw*dw*iv.w;
            t += __shfl_xor(t, 1); t += __shfl_xor(t, 2);   // 16 pose comps
            if (c4 == 0) zzl[(ks * 36 + i) * O + o] = zp - t;
        }
    }
    __syncthreads();
    float4* dst = (float4*)(g_zz + (size_t)bp * (KTOT * O));
    for (int f = tid; f < KTOT * O / 4; f += 512)
        dst[f] = ((float4*)zzl)[f];
}

// ============ E: segment softmax, writes rr' = rr * act =============
__global__ __launch_bounds__(256)
void e_kernel(const float* __restrict__ acts)
{
    const int tid = threadIdx.x;
    const int u   = blockIdx.x;
    const int b   = u / (CS * CS * 2);
    int r = u - b * (CS * CS * 2);
    const int child = r >> 1, half = r & 1;
    const int cr = child / CS, cl = child - cr * CS;
    const int cc = half * 8 + (tid >> 5), o = tid & 31;

    float zz[9];
    float vmax = -1e30f;
    #pragma unroll
    for (int kr = 0; kr < 3; ++kr) {
        int pr_ = cr - kr;
        #pragma unroll
        for (int kc = 0; kc < 3; ++kc) {
            int pc_ = cl - kc, si = kr * 3 + kc;
            float z = -1e30f;
            if (pr_ >= 0 && pr_ < P && pc_ >= 0 && pc_ < P) {
                int bpp = b * P2 + pr_ * P + pc_;
                z = g_zz[(size_t)bpp * (KTOT * O) + (si * CCAPS + cc) * O + o];
            }
            zz[si] = z;
            vmax = fmaxf(vmax, z);
        }
    }
    vmax = fmaxf(vmax, __shfl_xor(vmax, 1));
    vmax = fmaxf(vmax, __shfl_xor(vmax, 2));
    vmax = fmaxf(vmax, __shfl_xor(vmax, 4));
    vmax = fmaxf(vmax, __shfl_xor(vmax, 8));
    vmax = fmaxf(vmax, __shfl_xor(vmax, 16));

    float ps = 0.f;
    #pragma unroll
    for (int si = 0; si < 9; ++si) {
        float e = (zz[si] > -1e29f) ? expf(zz[si] - vmax) : 0.f;
        zz[si] = e;
        ps += e;
    }
    ps += __shfl_xor(ps, 1);
    ps += __shfl_xor(ps, 2);
    ps += __shfl_xor(ps, 4);
    ps += __shfl_xor(ps, 8);
    ps += __shfl_xor(ps, 16);
    float inv = 1.f / ps;

    #pragma unroll
    for (int kr = 0; kr < 3; ++kr) {
        int pr_ = cr - kr;
        #pragma unroll
        for (int kc = 0; kc < 3; ++kc) {
            int pc_ = cl - kc, si = kr * 3 + kc;
            if (pr_ >= 0 && pr_ < P && pc_ >= 0 && pc_ < P) {
                int bpp = b * P2 + pr_ * P + pc_;
                float av = acts[bpp * KTOT + si * CCAPS + cc];
                g_rrp[(size_t)bpp * (KTOT * O) + (si * CCAPS + cc) * O + o]
                    = zz[si] * inv * av;
            }
        }
    }
}

extern "C" void kernel_launch(void* const* d_in, const int* in_sizes, int n_in,
                              void* d_out, int out_size, void* d_ws, size_t ws_size,
                              hipStream_t stream)
{
    (void)in_sizes; (void)n_in; (void)out_size; (void)ws_size;

    const float* votes = (const float*)d_in[0];
    const float* acts  = (const float*)d_in[1];
    const float* bv    = (const float*)d_in[2];
    const float* ba    = (const float*)d_in[3];
    float* out = (float*)d_out;
    __half* hv = (__half*)d_ws;          // 59 MB fp16 votes copy

    v400_kernel<<<dim3(NBP), dim3(512), 0, stream>>>(votes, acts, hv, bv, ba, LAM0);
    e_kernel<<<dim3(EUNITS), dim3(256), 0, stream>>>(acts);
    m16_kernel<false><<<dim3(NBP), dim3(512), 0, stream>>>(hv, bv, ba, out, LAM1);
    e_kernel<<<dim3(EUNITS), dim3(256), 0, stream>>>(acts);
    m16_kernel<true ><<<dim3(NBP), dim3(512), 0, stream>>>(hv, bv, ba, out, LAM2);
}

// Round 9
// 250.745 us; speedup vs baseline: 1.0624x; 1.0533x over previous
//
#include <hip/hip_runtime.h>
#include <hip/hip_fp16.h>
#include <math.h>

// EM routing, hardcoded geometry: CHILD_SPACE=12, K=3, S=1 -> P=10,
// CHILD_CAPS=16, PARENT_CAPS=O=32, POSE=16, N=4, KTOT=144
// FINAL (session): R1 configuration — best measured 251.98 us.
// 8 experiments (occupancy, reg-cache MLP x3, grid split x2, prefetch ring,
// LDS-union residency) all landed 252-287 us; the ensemble is latency-
// structure-bound at ~2.5 TB/s with 400 barrier-phased blocks.
#define NB     4
#define P      10
#define P2     100
#define CS     12
#define CCAPS  16
#define KTOT   144
#define O      32
#define POSE   16
#define VSZ    73728          // KTOT*O*POSE elems per (b,p)
#define EPSF   1e-9f
#define LNF    22.2222222222222222f   // 100/(144/32)
#define TWO_PI 6.28318530717958647f
#define NBP    400
#define EUNITS (NB*CS*CS*2)   // 1152

#define LAM0 0.0005f          // 0.01*(1-0.95)
#define LAM1 0.000975f        // 0.01*(1-0.95^2)
#define LAM2 0.00142625f      // 0.01*(1-0.95^3)

__device__ float g_zz [NBP*KTOT*O];   // log-posteriors (M output)
__device__ float g_rrp[NBP*KTOT*O];   // rr' = rr * act (E output)

// number of parents covering child coord x (1-D): min(x+1, 3, 12-x)
__device__ __forceinline__ int npar(int x) {
    int a = x + 1, b = CS - x;
    int m = a < 3 ? a : 3;
    return m < b ? m : b;
}

// =========== V400: iter-0 m_step fully fused (fp32) + fp16 convert ==========
// grid 400 (bp), 1024 thr: tid = ks*128 + q, ks=0..7 (18 rows each), q = o*4+c4.
__global__ __launch_bounds__(1024, 8)
void v400_kernel(const float* __restrict__ votes, const float* __restrict__ acts,
                 __half* __restrict__ hv,
                 const float* __restrict__ beta_v, const float* __restrict__ beta_a,
                 float lam)
{
    __shared__ float  rr1[KTOT];                  // iter-0 rr' (o-independent)
    __shared__ float4 lm1[1024];                  // 16 KB
    __shared__ float4 lm2[1024];                  // 16 KB
    __shared__ float  lss[1024];                  // 4 KB
    __shared__ float4 ml[128];
    __shared__ float4 il[128];
    __shared__ float  zl[O];
    __shared__ float  costl[O];
    __shared__ __align__(16) float zzl[KTOT*O];   // 18 KB

    const int tid = threadIdx.x;
    const int bp  = blockIdx.x;
    const int p   = bp % P2;
    const int pr  = p / P, pc = p - pr * P;
    const int ks  = tid >> 7;          // 0..7, 18 rows each
    const int q   = tid & 127;
    const int o   = q >> 2;
    const int c4  = q & 3;

    if (tid < KTOT) {
        int kslot = tid >> 4;
        int kr = kslot / 3, kc = kslot - kr * 3;
        float ppc = (float)(npar(pr + kr) * npar(pc + kc));
        rr1[tid] = acts[bp * KTOT + tid] / (ppc * 32.0f + EPSF);
    }
    __syncthreads();

    const float* vb = votes + (size_t)bp * VSZ + (size_t)(ks * 18) * 512 + q * 4;
    __half*      hb = hv    + (size_t)bp * VSZ + (size_t)(ks * 18) * 512 + q * 4;
    float  s  = 0.f;
    float4 m1 = make_float4(0.f, 0.f, 0.f, 0.f);
    float4 m2 = make_float4(0.f, 0.f, 0.f, 0.f);
    #pragma unroll 6
    for (int i = 0; i < 18; ++i) {
        float  rp = rr1[ks * 18 + i];
        float4 v  = *(const float4*)(vb + i * 512);
        s += rp;
        m1.x += rp * v.x;       m1.y += rp * v.y;
        m1.z += rp * v.z;       m1.w += rp * v.w;
        m2.x += rp * v.x * v.x; m2.y += rp * v.y * v.y;
        m2.z += rp * v.z * v.z; m2.w += rp * v.w * v.w;
        __half2 ha  = __floats2half2_rn(v.x, v.y);
        __half2 hbv = __floats2half2_rn(v.z, v.w);
        uint2 st;
        st.x = *(unsigned int*)&ha;
        st.y = *(unsigned int*)&hbv;
        *(uint2*)(hb + i * 512) = st;
    }
    lm1[tid] = m1; lm2[tid] = m2; lss[tid] = s;
    __syncthreads();

    float lv2 = 0.f, cost_o = 0.f;
    if (tid < 128) {
        m1 = lm1[tid]; m2 = lm2[tid]; s = lss[tid];
        #pragma unroll
        for (int w = 1; w < 8; ++w) {
            float4 a = lm1[w * 128 + tid];
            float4 b = lm2[w * 128 + tid];
            m1.x += a.x; m1.y += a.y; m1.z += a.z; m1.w += a.w;
            m2.x += b.x; m2.y += b.y; m2.z += b.z; m2.w += b.w;
            s += lss[w * 128 + tid];
        }

        float denom = s + EPSF;
        float4 mean = make_float4(m1.x/denom, m1.y/denom, m1.z/denom, m1.w/denom);
        float4 var;
        var.x = fmaxf(m2.x/denom - mean.x*mean.x, 1e-30f);
        var.y = fmaxf(m2.y/denom - mean.y*mean.y, 1e-30f);
        var.z = fmaxf(m2.z/denom - mean.z*mean.z, 1e-30f);
        var.w = fmaxf(m2.w/denom - mean.w*mean.w, 1e-30f);
        float4 i2 = make_float4(0.5f/var.x, 0.5f/var.y, 0.5f/var.z, 0.5f/var.w);
        ml[tid] = mean; il[tid] = i2;
        float lve = logf(var.x+EPSF)+logf(var.y+EPSF)+logf(var.z+EPSF)+logf(var.w+EPSF);
        float l2  = logf(TWO_PI*var.x)+logf(TWO_PI*var.y)+logf(TWO_PI*var.z)+logf(TWO_PI*var.w);
        lve += __shfl_xor(lve, 1); lve += __shfl_xor(lve, 2);
        l2  += __shfl_xor(l2, 1);  l2  += __shfl_xor(l2, 2);
        lv2 = l2;
        cost_o = (16.f * beta_v[o] + 0.5f * lve) * s * LNF;
        if (c4 == 0) costl[o] = cost_o;
    }
    __syncthreads();
    if (tid < 128) {
        float cm = 0.f;
        #pragma unroll
        for (int i = 0; i < O; ++i) cm += costl[i];
        cm *= (1.f / 32.f);
        float sq = 0.f;
        #pragma unroll
        for (int i = 0; i < O; ++i) { float d = costl[i] - cm; sq += d * d; }
        float cstd = sqrtf(sq * (1.f / 32.f));
        float aj = 1.f / (1.f + expf(-lam * (beta_a[o] + (cm - cost_o) / (cstd + EPSF))));
        if (c4 == 0) zl[o] = logf(aj + EPSF) - 0.5f * lv2;
    }
    __syncthreads();

    // zz pass (fp32 re-read, L2/L3-warm)
    {
        float4 mean = ml[q];
        float4 iv   = il[q];
        float  zp   = zl[o];
        #pragma unroll 6
        for (int i = 0; i < 18; ++i) {
            float4 v = *(const float4*)(vb + i * 512);
            float dx = v.x - mean.x, dy = v.y - mean.y;
            float dz = v.z - mean.z, dw = v.w - mean.w;
            float t = dx*dx*iv.x + dy*dy*iv.y + dz*dz*iv.z + dw*dw*iv.w;
            t += __shfl_xor(t, 1); t += __shfl_xor(t, 2);   // 16 pose comps
            if (c4 == 0) zzl[(ks * 18 + i) * O + o] = zp - t;
        }
    }
    __syncthreads();
    float4* dst = (float4*)(g_zz + (size_t)bp * (KTOT * O));
    for (int f = tid; f < KTOT * O / 4; f += 1024)
        dst[f] = ((float4*)zzl)[f];
}

// ============ M16: full m_step from fp16 votes + rr' (grid 400) =============
// 1024 thr: tid = ks*128 + q, ks=0..7 (18 rows each), q = o*4 + c4 (4 comps).
template<bool LAST>
__global__ __launch_bounds__(1024, 8)
void m16_kernel(const __half* __restrict__ hv,
                const float* __restrict__ beta_v, const float* __restrict__ beta_a,
                float* __restrict__ out, float lam)
{
    __shared__ __align__(16) float rrp[KTOT*O];   // 18 KB; reused as zzl
    __shared__ float4 lm1[1024];                  // 16 KB
    __shared__ float4 lm2[1024];                  // 16 KB
    __shared__ float  lss[1024];                  // 4 KB
    __shared__ float4 ml[128];
    __shared__ float4 il[128];
    __shared__ float  zl[O];
    __shared__ float  costl[O];

    const int tid = threadIdx.x;
    const int bp  = blockIdx.x;
    const int ks  = tid >> 7;
    const int q   = tid & 127;
    const int o   = q >> 2;
    const int c4  = q & 3;

    // stage rr'
    for (int f = tid; f < KTOT * O / 4; f += 1024)
        ((float4*)rrp)[f] = ((const float4*)(g_rrp + (size_t)bp * (KTOT * O)))[f];
    __syncthreads();

    const __half* vb = hv + (size_t)bp * VSZ + (size_t)(ks * 18) * 512 + q * 4;
    float  s  = 0.f;
    float4 m1 = make_float4(0.f, 0.f, 0.f, 0.f);
    float4 m2 = make_float4(0.f, 0.f, 0.f, 0.f);
    #pragma unroll 6
    for (int i = 0; i < 18; ++i) {
        float rp = rrp[(ks * 18 + i) * O + o];
        uint2 u  = *(const uint2*)(vb + i * 512);
        float2 a = __half22float2(*(__half2*)&u.x);
        float2 b = __half22float2(*(__half2*)&u.y);
        s += rp;
        m1.x += rp * a.x;       m1.y += rp * a.y;
        m1.z += rp * b.x;       m1.w += rp * b.y;
        m2.x += rp * a.x * a.x; m2.y += rp * a.y * a.y;
        m2.z += rp * b.x * b.x; m2.w += rp * b.y * b.y;
    }
    lm1[tid] = m1; lm2[tid] = m2; lss[tid] = s;
    __syncthreads();

    float lv2 = 0.f, cost_o = 0.f;
    if (tid < 128) {
        m1 = lm1[tid]; m2 = lm2[tid]; s = lss[tid];
        #pragma unroll
        for (int w = 1; w < 8; ++w) {
            float4 a = lm1[w * 128 + tid];
            float4 b = lm2[w * 128 + tid];
            m1.x += a.x; m1.y += a.y; m1.z += a.z; m1.w += a.w;
            m2.x += b.x; m2.y += b.y; m2.z += b.z; m2.w += b.w;
            s += lss[w * 128 + tid];
        }

        float denom = s + EPSF;
        float4 mean = make_float4(m1.x/denom, m1.y/denom, m1.z/denom, m1.w/denom);
        float4 var;
        var.x = fmaxf(m2.x/denom - mean.x*mean.x, 1e-30f);
        var.y = fmaxf(m2.y/denom - mean.y*mean.y, 1e-30f);
        var.z = fmaxf(m2.z/denom - mean.z*mean.z, 1e-30f);
        var.w = fmaxf(m2.w/denom - mean.w*mean.w, 1e-30f);
        float4 i2 = make_float4(0.5f/var.x, 0.5f/var.y, 0.5f/var.z, 0.5f/var.w);
        ml[tid] = mean; il[tid] = i2;
        float lve = logf(var.x+EPSF)+logf(var.y+EPSF)+logf(var.z+EPSF)+logf(var.w+EPSF);
        float l2  = logf(TWO_PI*var.x)+logf(TWO_PI*var.y)+logf(TWO_PI*var.z)+logf(TWO_PI*var.w);
        lve += __shfl_xor(lve, 1); lve += __shfl_xor(lve, 2);
        l2  += __shfl_xor(l2, 1);  l2  += __shfl_xor(l2, 2);
        lv2 = l2;
        cost_o = (16.f * beta_v[o] + 0.5f * lve) * s * LNF;
        if (c4 == 0) costl[o] = cost_o;
    }
    __syncthreads();
    if (tid < 128) {
        float cm = 0.f;
        #pragma unroll
        for (int i = 0; i < O; ++i) cm += costl[i];
        cm *= (1.f / 32.f);
        float sq = 0.f;
        #pragma unroll
        for (int i = 0; i < O; ++i) { float d = costl[i] - cm; sq += d * d; }
        float cstd = sqrtf(sq * (1.f / 32.f));
        float aj = 1.f / (1.f + expf(-lam * (beta_a[o] + (cm - cost_o) / (cstd + EPSF))));
        if (LAST) {
            ((float4*)out)[bp * 128 + tid] = ml[tid];
            if (c4 == 0) out[(size_t)NBP * 512 + bp * O + o] = aj;
        } else {
            if (c4 == 0) zl[o] = logf(aj + EPSF) - 0.5f * lv2;
        }
    }
    if (LAST) return;
    __syncthreads();

    // zz pass (fp16 re-read, L2/L3-warm); zzl aliases rrp
    {
        float4 mean = ml[q];
        float4 iv   = il[q];
        float  zp   = zl[o];
        #pragma unroll 6
        for (int i = 0; i < 18; ++i) {
            uint2 u  = *(const uint2*)(vb + i * 512);
            float2 a = __half22float2(*(__half2*)&u.x);
            float2 b = __half22float2(*(__half2*)&u.y);
            float dx = a.x - mean.x, dy = a.y - mean.y;
            float dz = b.x - mean.z, dw = b.y - mean.w;
            float t = dx*dx*iv.x + dy*dy*iv.y + dz*dz*iv.z + dw*dw*iv.w;
            t += __shfl_xor(t, 1); t += __shfl_xor(t, 2);   // 16 pose comps
            if (c4 == 0) rrp[(ks * 18 + i) * O + o] = zp - t;
        }
    }
    __syncthreads();
    float4* dst = (float4*)(g_zz + (size_t)bp * (KTOT * O));
    for (int f = tid; f < KTOT * O / 4; f += 1024)
        dst[f] = ((float4*)rrp)[f];
}

// ============ E: segment softmax, writes rr' = rr * act =============
__global__ __launch_bounds__(256)
void e_kernel(const float* __restrict__ acts)
{
    const int tid = threadIdx.x;
    const int u   = blockIdx.x;
    const int b   = u / (CS * CS * 2);
    int r = u - b * (CS * CS * 2);
    const int child = r >> 1, half = r & 1;
    const int cr = child / CS, cl = child - cr * CS;
    const int cc = half * 8 + (tid >> 5), o = tid & 31;

    float zz[9];
    float vmax = -1e30f;
    #pragma unroll
    for (int kr = 0; kr < 3; ++kr) {
        int pr_ = cr - kr;
        #pragma unroll
        for (int kc = 0; kc < 3; ++kc) {
            int pc_ = cl - kc, si = kr * 3 + kc;
            float z = -1e30f;
            if (pr_ >= 0 && pr_ < P && pc_ >= 0 && pc_ < P) {
                int bpp = b * P2 + pr_ * P + pc_;
                z = g_zz[(size_t)bpp * (KTOT * O) + (si * CCAPS + cc) * O + o];
            }
            zz[si] = z;
            vmax = fmaxf(vmax, z);
        }
    }
    vmax = fmaxf(vmax, __shfl_xor(vmax, 1));
    vmax = fmaxf(vmax, __shfl_xor(vmax, 2));
    vmax = fmaxf(vmax, __shfl_xor(vmax, 4));
    vmax = fmaxf(vmax, __shfl_xor(vmax, 8));
    vmax = fmaxf(vmax, __shfl_xor(vmax, 16));

    float ps = 0.f;
    #pragma unroll
    for (int si = 0; si < 9; ++si) {
        float e = (zz[si] > -1e29f) ? expf(zz[si] - vmax) : 0.f;
        zz[si] = e;
        ps += e;
    }
    ps += __shfl_xor(ps, 1);
    ps += __shfl_xor(ps, 2);
    ps += __shfl_xor(ps, 4);
    ps += __shfl_xor(ps, 8);
    ps += __shfl_xor(ps, 16);
    float inv = 1.f / ps;

    #pragma unroll
    for (int kr = 0; kr < 3; ++kr) {
        int pr_ = cr - kr;
        #pragma unroll
        for (int kc = 0; kc < 3; ++kc) {
            int pc_ = cl - kc, si = kr * 3 + kc;
            if (pr_ >= 0 && pr_ < P && pc_ >= 0 && pc_ < P) {
                int bpp = b * P2 + pr_ * P + pc_;
                float av = acts[bpp * KTOT + si * CCAPS + cc];
                g_rrp[(size_t)bpp * (KTOT * O) + (si * CCAPS + cc) * O + o]
                    = zz[si] * inv * av;
            }
        }
    }
}

extern "C" void kernel_launch(void* const* d_in, const int* in_sizes, int n_in,
                              void* d_out, int out_size, void* d_ws, size_t ws_size,
                              hipStream_t stream)
{
    (void)in_sizes; (void)n_in; (void)out_size; (void)ws_size;

    const float* votes = (const float*)d_in[0];
    const float* acts  = (const float*)d_in[1];
    const float* bv    = (const float*)d_in[2];
    const float* ba    = (const float*)d_in[3];
    float* out = (float*)d_out;
    __half* hv = (__half*)d_ws;          // 59 MB fp16 votes copy

    v400_kernel<<<dim3(NBP), dim3(1024), 0, stream>>>(votes, acts, hv, bv, ba, LAM0);
    e_kernel<<<dim3(EUNITS), dim3(256), 0, stream>>>(acts);
    m16_kernel<false><<<dim3(NBP), dim3(1024), 0, stream>>>(hv, bv, ba, out, LAM1);
    e_kernel<<<dim3(EUNITS), dim3(256), 0, stream>>>(acts);
    m16_kernel<true ><<<dim3(NBP), dim3(1024), 0, stream>>>(hv, bv, ba, out, LAM2);
}

// Round 10
// 248.290 us; speedup vs baseline: 1.0729x; 1.0099x over previous
//
#include <hip/hip_runtime.h>
#include <hip/hip_fp16.h>
#include <math.h>

// EM routing, hardcoded geometry: CHILD_SPACE=12, K=3, S=1 -> P=10,
// CHILD_CAPS=16, PARENT_CAPS=O=32, POSE=16, N=4, KTOT=144
// R10: R1 structure, but v400's hv convert+store moved from the cold-HBM
// m-loop (pass 1) into the L3-warm zz pass (pass 2). Stores share vmcnt
// with loads on CDNA; removing them from pass 1 un-entangles the cold
// load stream (the session's one untried de-serialization).
#define NB     4
#define P      10
#define P2     100
#define CS     12
#define CCAPS  16
#define KTOT   144
#define O      32
#define POSE   16
#define VSZ    73728          // KTOT*O*POSE elems per (b,p)
#define EPSF   1e-9f
#define LNF    22.2222222222222222f   // 100/(144/32)
#define TWO_PI 6.28318530717958647f
#define NBP    400
#define EUNITS (NB*CS*CS*2)   // 1152

#define LAM0 0.0005f          // 0.01*(1-0.95)
#define LAM1 0.000975f        // 0.01*(1-0.95^2)
#define LAM2 0.00142625f      // 0.01*(1-0.95^3)

__device__ float g_zz [NBP*KTOT*O];   // log-posteriors (M output)
__device__ float g_rrp[NBP*KTOT*O];   // rr' = rr * act (E output)

// number of parents covering child coord x (1-D): min(x+1, 3, 12-x)
__device__ __forceinline__ int npar(int x) {
    int a = x + 1, b = CS - x;
    int m = a < 3 ? a : 3;
    return m < b ? m : b;
}

// =========== V400: iter-0 m_step fully fused (fp32) + fp16 convert ==========
// grid 400 (bp), 1024 thr: tid = ks*128 + q, ks=0..7 (18 rows each), q = o*4+c4.
// Pass 1: PURE-LOAD accumulate (no stores in the vmcnt stream, cold HBM).
// Pass 2: L3-warm re-read -> zz + fp16 convert + hv store.
__global__ __launch_bounds__(1024, 8)
void v400_kernel(const float* __restrict__ votes, const float* __restrict__ acts,
                 __half* __restrict__ hv,
                 const float* __restrict__ beta_v, const float* __restrict__ beta_a,
                 float lam)
{
    __shared__ float  rr1[KTOT];                  // iter-0 rr' (o-independent)
    __shared__ float4 lm1[1024];                  // 16 KB
    __shared__ float4 lm2[1024];                  // 16 KB
    __shared__ float  lss[1024];                  // 4 KB
    __shared__ float4 ml[128];
    __shared__ float4 il[128];
    __shared__ float  zl[O];
    __shared__ float  costl[O];
    __shared__ __align__(16) float zzl[KTOT*O];   // 18 KB

    const int tid = threadIdx.x;
    const int bp  = blockIdx.x;
    const int p   = bp % P2;
    const int pr  = p / P, pc = p - pr * P;
    const int ks  = tid >> 7;          // 0..7, 18 rows each
    const int q   = tid & 127;
    const int o   = q >> 2;
    const int c4  = q & 3;

    if (tid < KTOT) {
        int kslot = tid >> 4;
        int kr = kslot / 3, kc = kslot - kr * 3;
        float ppc = (float)(npar(pr + kr) * npar(pc + kc));
        rr1[tid] = acts[bp * KTOT + tid] / (ppc * 32.0f + EPSF);
    }
    __syncthreads();

    const float* vb = votes + (size_t)bp * VSZ + (size_t)(ks * 18) * 512 + q * 4;
    __half*      hb = hv    + (size_t)bp * VSZ + (size_t)(ks * 18) * 512 + q * 4;
    float  s  = 0.f;
    float4 m1 = make_float4(0.f, 0.f, 0.f, 0.f);
    float4 m2 = make_float4(0.f, 0.f, 0.f, 0.f);
    #pragma unroll
    for (int i = 0; i < 18; ++i) {
        float  rp = rr1[ks * 18 + i];
        float4 v  = *(const float4*)(vb + i * 512);
        s += rp;
        m1.x += rp * v.x;       m1.y += rp * v.y;
        m1.z += rp * v.z;       m1.w += rp * v.w;
        m2.x += rp * v.x * v.x; m2.y += rp * v.y * v.y;
        m2.z += rp * v.z * v.z; m2.w += rp * v.w * v.w;
    }
    lm1[tid] = m1; lm2[tid] = m2; lss[tid] = s;
    __syncthreads();

    float lv2 = 0.f, cost_o = 0.f;
    if (tid < 128) {
        m1 = lm1[tid]; m2 = lm2[tid]; s = lss[tid];
        #pragma unroll
        for (int w = 1; w < 8; ++w) {
            float4 a = lm1[w * 128 + tid];
            float4 b = lm2[w * 128 + tid];
            m1.x += a.x; m1.y += a.y; m1.z += a.z; m1.w += a.w;
            m2.x += b.x; m2.y += b.y; m2.z += b.z; m2.w += b.w;
            s += lss[w * 128 + tid];
        }

        float denom = s + EPSF;
        float4 mean = make_float4(m1.x/denom, m1.y/denom, m1.z/denom, m1.w/denom);
        float4 var;
        var.x = fmaxf(m2.x/denom - mean.x*mean.x, 1e-30f);
        var.y = fmaxf(m2.y/denom - mean.y*mean.y, 1e-30f);
        var.z = fmaxf(m2.z/denom - mean.z*mean.z, 1e-30f);
        var.w = fmaxf(m2.w/denom - mean.w*mean.w, 1e-30f);
        float4 i2 = make_float4(0.5f/var.x, 0.5f/var.y, 0.5f/var.z, 0.5f/var.w);
        ml[tid] = mean; il[tid] = i2;
        float lve = logf(var.x+EPSF)+logf(var.y+EPSF)+logf(var.z+EPSF)+logf(var.w+EPSF);
        float l2  = logf(TWO_PI*var.x)+logf(TWO_PI*var.y)+logf(TWO_PI*var.z)+logf(TWO_PI*var.w);
        lve += __shfl_xor(lve, 1); lve += __shfl_xor(lve, 2);
        l2  += __shfl_xor(l2, 1);  l2  += __shfl_xor(l2, 2);
        lv2 = l2;
        cost_o = (16.f * beta_v[o] + 0.5f * lve) * s * LNF;
        if (c4 == 0) costl[o] = cost_o;
    }
    __syncthreads();
    if (tid < 128) {
        float cm = 0.f;
        #pragma unroll
        for (int i = 0; i < O; ++i) cm += costl[i];
        cm *= (1.f / 32.f);
        float sq = 0.f;
        #pragma unroll
        for (int i = 0; i < O; ++i) { float d = costl[i] - cm; sq += d * d; }
        float cstd = sqrtf(sq * (1.f / 32.f));
        float aj = 1.f / (1.f + expf(-lam * (beta_a[o] + (cm - cost_o) / (cstd + EPSF))));
        if (c4 == 0) zl[o] = logf(aj + EPSF) - 0.5f * lv2;
    }
    __syncthreads();

    // zz pass (fp32 re-read, L2/L3-warm) + fp16 convert + hv store
    {
        float4 mean = ml[q];
        float4 iv   = il[q];
        float  zp   = zl[o];
        #pragma unroll 6
        for (int i = 0; i < 18; ++i) {
            float4 v = *(const float4*)(vb + i * 512);
            __half2 ha  = __floats2half2_rn(v.x, v.y);
            __half2 hbv = __floats2half2_rn(v.z, v.w);
            uint2 st;
            st.x = *(unsigned int*)&ha;
            st.y = *(unsigned int*)&hbv;
            *(uint2*)(hb + i * 512) = st;
            float dx = v.x - mean.x, dy = v.y - mean.y;
            float dz = v.z - mean.z, dw = v.w - mean.w;
            float t = dx*dx*iv.x + dy*dy*iv.y + dz*dz*iv.z + dw*dw*iv.w;
            t += __shfl_xor(t, 1); t += __shfl_xor(t, 2);   // 16 pose comps
            if (c4 == 0) zzl[(ks * 18 + i) * O + o] = zp - t;
        }
    }
    __syncthreads();
    float4* dst = (float4*)(g_zz + (size_t)bp * (KTOT * O));
    for (int f = tid; f < KTOT * O / 4; f += 1024)
        dst[f] = ((float4*)zzl)[f];
}

// ============ M16: full m_step from fp16 votes + rr' (grid 400) =============
// 1024 thr: tid = ks*128 + q, ks=0..7 (18 rows each), q = o*4 + c4 (4 comps).
template<bool LAST>
__global__ __launch_bounds__(1024, 8)
void m16_kernel(const __half* __restrict__ hv,
                const float* __restrict__ beta_v, const float* __restrict__ beta_a,
                float* __restrict__ out, float lam)
{
    __shared__ __align__(16) float rrp[KTOT*O];   // 18 KB; reused as zzl
    __shared__ float4 lm1[1024];                  // 16 KB
    __shared__ float4 lm2[1024];                  // 16 KB
    __shared__ float  lss[1024];                  // 4 KB
    __shared__ float4 ml[128];
    __shared__ float4 il[128];
    __shared__ float  zl[O];
    __shared__ float  costl[O];

    const int tid = threadIdx.x;
    const int bp  = blockIdx.x;
    const int ks  = tid >> 7;
    const int q   = tid & 127;
    const int o   = q >> 2;
    const int c4  = q & 3;

    // stage rr'
    for (int f = tid; f < KTOT * O / 4; f += 1024)
        ((float4*)rrp)[f] = ((const float4*)(g_rrp + (size_t)bp * (KTOT * O)))[f];
    __syncthreads();

    const __half* vb = hv + (size_t)bp * VSZ + (size_t)(ks * 18) * 512 + q * 4;
    float  s  = 0.f;
    float4 m1 = make_float4(0.f, 0.f, 0.f, 0.f);
    float4 m2 = make_float4(0.f, 0.f, 0.f, 0.f);
    #pragma unroll 6
    for (int i = 0; i < 18; ++i) {
        float rp = rrp[(ks * 18 + i) * O + o];
        uint2 u  = *(const uint2*)(vb + i * 512);
        float2 a = __half22float2(*(__half2*)&u.x);
        float2 b = __half22float2(*(__half2*)&u.y);
        s += rp;
        m1.x += rp * a.x;       m1.y += rp * a.y;
        m1.z += rp * b.x;       m1.w += rp * b.y;
        m2.x += rp * a.x * a.x; m2.y += rp * a.y * a.y;
        m2.z += rp * b.x * b.x; m2.w += rp * b.y * b.y;
    }
    lm1[tid] = m1; lm2[tid] = m2; lss[tid] = s;
    __syncthreads();

    float lv2 = 0.f, cost_o = 0.f;
    if (tid < 128) {
        m1 = lm1[tid]; m2 = lm2[tid]; s = lss[tid];
        #pragma unroll
        for (int w = 1; w < 8; ++w) {
            float4 a = lm1[w * 128 + tid];
            float4 b = lm2[w * 128 + tid];
            m1.x += a.x; m1.y += a.y; m1.z += a.z; m1.w += a.w;
            m2.x += b.x; m2.y += b.y; m2.z += b.z; m2.w += b.w;
            s += lss[w * 128 + tid];
        }

        float denom = s + EPSF;
        float4 mean = make_float4(m1.x/denom, m1.y/denom, m1.z/denom, m1.w/denom);
        float4 var;
        var.x = fmaxf(m2.x/denom - mean.x*mean.x, 1e-30f);
        var.y = fmaxf(m2.y/denom - mean.y*mean.y, 1e-30f);
        var.z = fmaxf(m2.z/denom - mean.z*mean.z, 1e-30f);
        var.w = fmaxf(m2.w/denom - mean.w*mean.w, 1e-30f);
        float4 i2 = make_float4(0.5f/var.x, 0.5f/var.y, 0.5f/var.z, 0.5f/var.w);
        ml[tid] = mean; il[tid] = i2;
        float lve = logf(var.x+EPSF)+logf(var.y+EPSF)+logf(var.z+EPSF)+logf(var.w+EPSF);
        float l2  = logf(TWO_PI*var.x)+logf(TWO_PI*var.y)+logf(TWO_PI*var.z)+logf(TWO_PI*var.w);
        lve += __shfl_xor(lve, 1); lve += __shfl_xor(lve, 2);
        l2  += __shfl_xor(l2, 1);  l2  += __shfl_xor(l2, 2);
        lv2 = l2;
        cost_o = (16.f * beta_v[o] + 0.5f * lve) * s * LNF;
        if (c4 == 0) costl[o] = cost_o;
    }
    __syncthreads();
    if (tid < 128) {
        float cm = 0.f;
        #pragma unroll
        for (int i = 0; i < O; ++i) cm += costl[i];
        cm *= (1.f / 32.f);
        float sq = 0.f;
        #pragma unroll
        for (int i = 0; i < O; ++i) { float d = costl[i] - cm; sq += d * d; }
        float cstd = sqrtf(sq * (1.f / 32.f));
        float aj = 1.f / (1.f + expf(-lam * (beta_a[o] + (cm - cost_o) / (cstd + EPSF))));
        if (LAST) {
            ((float4*)out)[bp * 128 + tid] = ml[tid];
            if (c4 == 0) out[(size_t)NBP * 512 + bp * O + o] = aj;
        } else {
            if (c4 == 0) zl[o] = logf(aj + EPSF) - 0.5f * lv2;
        }
    }
    if (LAST) return;
    __syncthreads();

    // zz pass (fp16 re-read, L2/L3-warm); zzl aliases rrp
    {
        float4 mean = ml[q];
        float4 iv   = il[q];
        float  zp   = zl[o];
        #pragma unroll 6
        for (int i = 0; i < 18; ++i) {
            uint2 u  = *(const uint2*)(vb + i * 512);
            float2 a = __half22float2(*(__half2*)&u.x);
            float2 b = __half22float2(*(__half2*)&u.y);
            float dx = a.x - mean.x, dy = a.y - mean.y;
            float dz = b.x - mean.z, dw = b.y - mean.w;
            float t = dx*dx*iv.x + dy*dy*iv.y + dz*dz*iv.z + dw*dw*iv.w;
            t += __shfl_xor(t, 1); t += __shfl_xor(t, 2);   // 16 pose comps
            if (c4 == 0) rrp[(ks * 18 + i) * O + o] = zp - t;
        }
    }
    __syncthreads();
    float4* dst = (float4*)(g_zz + (size_t)bp * (KTOT * O));
    for (int f = tid; f < KTOT * O / 4; f += 1024)
        dst[f] = ((float4*)rrp)[f];
}

// ============ E: segment softmax, writes rr' = rr * act =============
__global__ __launch_bounds__(256)
void e_kernel(const float* __restrict__ acts)
{
    const int tid = threadIdx.x;
    const int u   = blockIdx.x;
    const int b   = u / (CS * CS * 2);
    int r = u - b * (CS * CS * 2);
    const int child = r >> 1, half = r & 1;
    const int cr = child / CS, cl = child - cr * CS;
    const int cc = half * 8 + (tid >> 5), o = tid & 31;

    float zz[9];
    float vmax = -1e30f;
    #pragma unroll
    for (int kr = 0; kr < 3; ++kr) {
        int pr_ = cr - kr;
        #pragma unroll
        for (int kc = 0; kc < 3; ++kc) {
            int pc_ = cl - kc, si = kr * 3 + kc;
            float z = -1e30f;
            if (pr_ >= 0 && pr_ < P && pc_ >= 0 && pc_ < P) {
                int bpp = b * P2 + pr_ * P + pc_;
                z = g_zz[(size_t)bpp * (KTOT * O) + (si * CCAPS + cc) * O + o];
            }
            zz[si] = z;
            vmax = fmaxf(vmax, z);
        }
    }
    vmax = fmaxf(vmax, __shfl_xor(vmax, 1));
    vmax = fmaxf(vmax, __shfl_xor(vmax, 2));
    vmax = fmaxf(vmax, __shfl_xor(vmax, 4));
    vmax = fmaxf(vmax, __shfl_xor(vmax, 8));
    vmax = fmaxf(vmax, __shfl_xor(vmax, 16));

    float ps = 0.f;
    #pragma unroll
    for (int si = 0; si < 9; ++si) {
        float e = (zz[si] > -1e29f) ? expf(zz[si] - vmax) : 0.f;
        zz[si] = e;
        ps += e;
    }
    ps += __shfl_xor(ps, 1);
    ps += __shfl_xor(ps, 2);
    ps += __shfl_xor(ps, 4);
    ps += __shfl_xor(ps, 8);
    ps += __shfl_xor(ps, 16);
    float inv = 1.f / ps;

    #pragma unroll
    for (int kr = 0; kr < 3; ++kr) {
        int pr_ = cr - kr;
        #pragma unroll
        for (int kc = 0; kc < 3; ++kc) {
            int pc_ = cl - kc, si = kr * 3 + kc;
            if (pr_ >= 0 && pr_ < P && pc_ >= 0 && pc_ < P) {
                int bpp = b * P2 + pr_ * P + pc_;
                float av = acts[bpp * KTOT + si * CCAPS + cc];
                g_rrp[(size_t)bpp * (KTOT * O) + (si * CCAPS + cc) * O + o]
                    = zz[si] * inv * av;
            }
        }
    }
}

extern "C" void kernel_launch(void* const* d_in, const int* in_sizes, int n_in,
                              void* d_out, int out_size, void* d_ws, size_t ws_size,
                              hipStream_t stream)
{
    (void)in_sizes; (void)n_in; (void)out_size; (void)ws_size;

    const float* votes = (const float*)d_in[0];
    const float* acts  = (const float*)d_in[1];
    const float* bv    = (const float*)d_in[2];
    const float* ba    = (const float*)d_in[3];
    float* out = (float*)d_out;
    __half* hv = (__half*)d_ws;          // 59 MB fp16 votes copy

    v400_kernel<<<dim3(NBP), dim3(1024), 0, stream>>>(votes, acts, hv, bv, ba, LAM0);
    e_kernel<<<dim3(EUNITS), dim3(256), 0, stream>>>(acts);
    m16_kernel<false><<<dim3(NBP), dim3(1024), 0, stream>>>(hv, bv, ba, out, LAM1);
    e_kernel<<<dim3(EUNITS), dim3(256), 0, stream>>>(acts);
    m16_kernel<true ><<<dim3(NBP), dim3(1024), 0, stream>>>(hv, bv, ba, out, LAM2);
}